// Round 1
// baseline (9532.916 us; speedup 1.0000x reference)
//
#include <hip/hip_runtime.h>

#define WIDTH 1024
#define NHH 16
#define HDD 64
#define MBSZ 16
#define BBB 4
#define LLL 2048
#define NCHUNK 128

typedef __attribute__((ext_vector_type(4))) float f32x4;
typedef __attribute__((ext_vector_type(8))) short short8;

__device__ __forceinline__ short f2bf(float f) {
  unsigned u = __float_as_uint(f);
  u = (u + 0x7FFFu + ((u >> 16) & 1u)) >> 16;  // RNE f32->bf16
  return (short)u;
}
__device__ __forceinline__ float gelu_f(float x) {
  float x2 = x * x;
  float t = tanhf(0.79788456f * x * (1.0f + 0.044715f * x2));
  return 0.5f * x * (1.0f + t);
}
__device__ __forceinline__ float gelu_bwd_f(float x) {
  float x2 = x * x;
  float t = tanhf(0.79788456f * x * (1.0f + 0.044715f * x2));
  return 0.5f * x * ((1.0f - t * t) * (0.79788456f + 0.1070322243f * x2)) + 0.5f * (1.0f + t);
}

// ---------------- C[M=8192][1024] = A[8192][1024] @ W[1024][1024]^T (bf16 MFMA, fp32 in/out)
__global__ __launch_bounds__(256) void gemm_bt(const float* __restrict__ A,
                                               const float* __restrict__ W,
                                               float* __restrict__ C) {
  __shared__ __align__(16) short sA[64][40];  // +8 pad: conflict-free b128 frag reads
  __shared__ __align__(16) short sB[64][40];
  const int tid = threadIdx.x;
  const int m0 = blockIdx.x * 64, n0 = blockIdx.y * 64;
  const int srow = tid >> 2, sk = (tid & 3) * 8;
  const int wv = tid >> 6, ln = tid & 63;
  const int fr = ln & 15, kh = (ln >> 4) * 8;
  f32x4 acc[4];
#pragma unroll
  for (int s = 0; s < 4; ++s) acc[s] = (f32x4){0.f, 0.f, 0.f, 0.f};
  const float* ga = A + (long)(m0 + srow) * 1024 + sk;
  const float* gw = W + (long)(n0 + srow) * 1024 + sk;
  for (int k0 = 0; k0 < 1024; k0 += 32) {
    f32x4 a0 = *(const f32x4*)(ga + k0);
    f32x4 a1 = *(const f32x4*)(ga + k0 + 4);
    f32x4 w0 = *(const f32x4*)(gw + k0);
    f32x4 w1 = *(const f32x4*)(gw + k0 + 4);
    short8 pa, pw;
    pa[0] = f2bf(a0[0]); pa[1] = f2bf(a0[1]); pa[2] = f2bf(a0[2]); pa[3] = f2bf(a0[3]);
    pa[4] = f2bf(a1[0]); pa[5] = f2bf(a1[1]); pa[6] = f2bf(a1[2]); pa[7] = f2bf(a1[3]);
    pw[0] = f2bf(w0[0]); pw[1] = f2bf(w0[1]); pw[2] = f2bf(w0[2]); pw[3] = f2bf(w0[3]);
    pw[4] = f2bf(w1[0]); pw[5] = f2bf(w1[1]); pw[6] = f2bf(w1[2]); pw[7] = f2bf(w1[3]);
    *(short8*)&sA[srow][sk] = pa;
    *(short8*)&sB[srow][sk] = pw;
    __syncthreads();
    short8 af = *(const short8*)&sA[wv * 16 + fr][kh];
#pragma unroll
    for (int s = 0; s < 4; ++s) {
      short8 bf8 = *(const short8*)&sB[s * 16 + fr][kh];
      acc[s] = __builtin_amdgcn_mfma_f32_16x16x32_bf16(af, bf8, acc[s], 0, 0, 0);
    }
    __syncthreads();
  }
  const int orow = m0 + wv * 16 + (ln >> 4) * 4;  // D: row=(lane>>4)*4+reg, col=lane&15
#pragma unroll
  for (int s = 0; s < 4; ++s)
#pragma unroll
    for (int q = 0; q < 4; ++q)
      C[(long)(orow + q) * 1024 + n0 + s * 16 + fr] = acc[s][q];
}

// ---------------- lr_eta[b,h,t] = sigmoid(hs[t]·lr_w[h] + lr_b[h]) / 64
__global__ __launch_bounds__(256) void lr_kernel(const float* __restrict__ hs,
                                                 const float* __restrict__ lrw,
                                                 const float* __restrict__ lrb,
                                                 float* __restrict__ out) {
  __shared__ __align__(16) float row[1024];
  const int t = blockIdx.x, tid = threadIdx.x;
  *(f32x4*)&row[tid * 4] = *(const f32x4*)&hs[(long)t * 1024 + tid * 4];
  __syncthreads();
  const int hh = tid >> 4, j = tid & 15;
  const float* wrow = lrw + hh * 1024;
  float s = 0.f;
#pragma unroll 4
  for (int m = 0; m < 16; ++m) {
    const int c = j * 4 + m * 64;
    f32x4 x = *(const f32x4*)&row[c];
    f32x4 w = *(const f32x4*)&wrow[c];
    s += x[0] * w[0] + x[1] * w[1] + x[2] * w[2] + x[3] * w[3];
  }
#pragma unroll
  for (int o = 8; o; o >>= 1) s += __shfl_xor(s, o, 16);
  if (j == 0) {
    const float v = s + lrb[hh];
    const float sg = 1.f / (1.f + expf(-v));
    const int b = t >> 11, tr = t & 2047;
    out[((b << 4) + hh) * 2048 + tr] = sg * (1.f / 64.f);
  }
}

// ---------------- sequential TTT scan: one block per (b,h)
__global__ __launch_bounds__(256, 1) void scan_kernel(
    float* __restrict__ Qb, const float* __restrict__ Kb, const float* __restrict__ Vb,
    const float* __restrict__ LRb, const float* __restrict__ lti,
    const float* __restrict__ nw, const float* __restrict__ nb,
    const float* __restrict__ W1in, const float* __restrict__ b1in,
    const float* __restrict__ W2in, const float* __restrict__ b2in,
    float* __restrict__ W2S) {
  // W1 state col-major + XOR swizzle (chunk c4 of col p stored at c4^(p&7)) -> conflict-free b128
  __shared__ __align__(16) float sW1c[256 * 64];
  __shared__ __align__(16) float sX2[16][257];
  __shared__ __align__(16) float sXb[16][257];
  __shared__ __align__(16) float sX1[16][68];
  __shared__ __align__(16) float sXQ[16][68];
  __shared__ __align__(16) float sTg[16][68];
  __shared__ __align__(16) float sZ2[16][68];
  __shared__ __align__(16) float sG2[16][68];
  __shared__ __align__(16) float sC[16][17];
  __shared__ __align__(16) float sB1[256];
  __shared__ __align__(16) float sB2[64];
  __shared__ float sLr[16];
  __shared__ float sTok[16];
  __shared__ __align__(16) float sLnw[64];
  __shared__ __align__(16) float sLnb[64];

  const int bh = blockIdx.x;
  const int b = bh >> 4, h = bh & 15;
  const int tid = threadIdx.x;
  const int p = tid;                       // column owner
  const int d64 = tid & 63, ig = tid >> 6; // (d, i-group) for 16x64 outputs

  for (int e = tid; e < 64 * 256; e += 256) {
    int pd = e & 255, dd = e >> 8;
    sW1c[pd * 64 + (((dd >> 2) ^ (pd & 7)) << 2) + (dd & 3)] = W1in[h * 16384 + e];
  }
  sB1[tid] = b1in[h * 256 + tid];
  if (tid < 64) { sB2[tid] = b2in[h * 64 + tid]; sLnw[tid] = nw[h * 64 + tid]; sLnb[tid] = nb[h * 64 + tid]; }
  if (tid < 16) sTok[tid] = fmaxf(1.0f / (float)(tid + 1) + lti[tid], 0.0f);
  __syncthreads();

  float* __restrict__ W2s = W2S + (long)bh * 16384;

  for (int n = 0; n < NCHUNK; ++n) {
    const long gbase = ((long)(b * LLL + n * MBSZ)) * WIDTH + h * HDD;
    // ---- load chunk
    for (int e = tid; e < 16 * 64; e += 256) {
      int i = e >> 6, d = e & 63;
      float kv = Kb[gbase + (long)i * WIDTH + d];
      sX1[i][d] = kv;
      sXQ[i][d] = Qb[gbase + (long)i * WIDTH + d];
      sTg[i][d] = Vb[gbase + (long)i * WIDTH + d] - kv;
    }
    if (tid < 16) sLr[tid] = LRb[(long)bh * 2048 + n * MBSZ + tid];
    __syncthreads();  // A

    // ---- step1: Z1 col & XQ@W1 col (regs); X2 -> LDS
    float z1[16], q1[16];
    {
      const float bp = sB1[p];
#pragma unroll
      for (int i = 0; i < 16; ++i) { z1[i] = bp; q1[i] = 0.f; }
#pragma unroll 4
      for (int dq = 0; dq < 16; ++dq) {
        const f32x4 w = *(const f32x4*)&sW1c[p * 64 + ((dq ^ (p & 7)) << 2)];
#pragma unroll
        for (int i = 0; i < 16; ++i) {
          const f32x4 x = *(const f32x4*)&sX1[i][dq * 4];
          const f32x4 q = *(const f32x4*)&sXQ[i][dq * 4];
          z1[i] += x[0] * w[0] + x[1] * w[1] + x[2] * w[2] + x[3] * w[3];
          q1[i] += q[0] * w[0] + q[1] * w[1] + q[2] * w[2] + q[3] * w[3];
        }
      }
#pragma unroll
      for (int i = 0; i < 16; ++i) sX2[i][p] = gelu_f(z1[i]);
    }
    // ---- C1[i][j] = (i>=j) ? tok[i]*lr[j]*(XQ·X1^T + 1) : 0   (folds eta*Attn1 + eta_tril)
    {
      const int ci = tid >> 4, cj = tid & 15;
      float a = 0.f;
#pragma unroll 4
      for (int dq = 0; dq < 16; ++dq) {
        const f32x4 xq = *(const f32x4*)&sXQ[ci][dq * 4];
        const f32x4 xk = *(const f32x4*)&sX1[cj][dq * 4];
        a += xq[0] * xk[0] + xq[1] * xk[1] + xq[2] * xk[2] + xq[3] * xk[3];
      }
      sC[ci][cj] = (ci >= cj) ? sTok[ci] * sLr[cj] * (a + 1.0f) : 0.0f;
    }
    __syncthreads();  // B

    // ---- Z2 = X2@W2 + b2
    {
      const float* __restrict__ w2p = (n == 0) ? (W2in + h * 16384) : W2s;
      float za0 = 0, za1 = 0, za2 = 0, za3 = 0;
#pragma unroll 8
      for (int pp = 0; pp < 256; ++pp) {
        const float w = w2p[pp * 64 + d64];
        za0 += sX2[ig * 4 + 0][pp] * w;
        za1 += sX2[ig * 4 + 1][pp] * w;
        za2 += sX2[ig * 4 + 2][pp] * w;
        za3 += sX2[ig * 4 + 3][pp] * w;
      }
      const float bb2 = sB2[d64];
      sZ2[ig * 4 + 0][d64] = za0 + bb2;
      sZ2[ig * 4 + 1][d64] = za1 + bb2;
      sZ2[ig * 4 + 2][d64] = za2 + bb2;
      sZ2[ig * 4 + 3][d64] = za3 + bb2;
    }
    __syncthreads();  // C

    // ---- gZ2 = ln_l2_bwd(Z2, V-K)
    {
      const int i = tid >> 4, j = tid & 15;
      const f32x4 z = *(const f32x4*)&sZ2[i][j * 4];
      float s1 = z[0] + z[1] + z[2] + z[3];
      float s2 = z[0] * z[0] + z[1] * z[1] + z[2] * z[2] + z[3] * z[3];
#pragma unroll
      for (int o = 8; o; o >>= 1) { s1 += __shfl_xor(s1, o, 16); s2 += __shfl_xor(s2, o, 16); }
      const float mu = s1 * (1.f / 64.f);
      const float var = s2 * (1.f / 64.f) - mu * mu;
      const float rstd = rsqrtf(var + 1e-6f);
      const f32x4 g = *(const f32x4*)&sLnw[j * 4];
      const f32x4 bb = *(const f32x4*)&sLnb[j * 4];
      const f32x4 tg = *(const f32x4*)&sTg[i][j * 4];
      f32x4 xh, gx;
      float a1 = 0.f, a2 = 0.f;
#pragma unroll
      for (int e = 0; e < 4; ++e) {
        xh[e] = (z[e] - mu) * rstd;
        gx[e] = (g[e] * xh[e] + bb[e] - tg[e]) * g[e];
        a1 += gx[e]; a2 += gx[e] * xh[e];
      }
#pragma unroll
      for (int o = 8; o; o >>= 1) { a1 += __shfl_xor(a1, o, 16); a2 += __shfl_xor(a2, o, 16); }
      const float m1 = a1 * (1.f / 64.f), m2 = a2 * (1.f / 64.f);
      f32x4 o4;
#pragma unroll
      for (int e = 0; e < 4; ++e) o4[e] = (gx[e] - m1 - xh[e] * m2) * rstd;
      *(f32x4*)&sG2[i][j * 4] = o4;
    }
    __syncthreads();  // D

    // ---- gZ1 col = (gZ2 @ W2^T) * gelu_bwd(Z1)   (stays in regs; all consumers column-local)
    float g1r[16];
    {
      float acc[16];
#pragma unroll
      for (int i = 0; i < 16; ++i) acc[i] = 0.f;
      const float* __restrict__ w2p = (n == 0) ? (W2in + h * 16384) : W2s;
      const float* __restrict__ wrow = w2p + p * 64;
#pragma unroll 4
      for (int dq = 0; dq < 16; ++dq) {
        const f32x4 w = *(const f32x4*)&wrow[dq * 4];
#pragma unroll
        for (int i = 0; i < 16; ++i) {
          const f32x4 gg = *(const f32x4*)&sG2[i][dq * 4];
          acc[i] += gg[0] * w[0] + gg[1] * w[1] + gg[2] * w[2] + gg[3] * w[3];
        }
      }
#pragma unroll
      for (int i = 0; i < 16; ++i) g1r[i] = acc[i] * gelu_bwd_f(z1[i]);
    }
    // ---- X2_bar col = gelu(XQ@W1 + b1 - C1@gZ1)
    {
#pragma unroll
      for (int i = 0; i < 16; ++i) {
        float v = q1[i] + sB1[p];
        for (int j = 0; j <= i; ++j) v -= sC[i][j] * g1r[j];
        sXb[i][p] = gelu_f(v);
      }
    }
    __syncthreads();  // E

    // ---- C2[i][j] = (i>=j) ? tok[i]*lr[j]*(X2_bar·X2^T + 1) : 0
    {
      const int ci = tid >> 4, cj = tid & 15;
      float a = 0.f;
#pragma unroll 8
      for (int pp = 0; pp < 256; ++pp) a += sXb[ci][pp] * sX2[cj][pp];
      sC[ci][cj] = (ci >= cj) ? sTok[ci] * sLr[cj] * (a + 1.0f) : 0.0f;
    }
    __syncthreads();  // F

    // ---- Z2_bar = X2_bar@W2 + b2 - C2@gZ2
    {
      const float* __restrict__ w2p = (n == 0) ? (W2in + h * 16384) : W2s;
      float za[4] = {0.f, 0.f, 0.f, 0.f};
#pragma unroll 8
      for (int pp = 0; pp < 256; ++pp) {
        const float w = w2p[pp * 64 + d64];
#pragma unroll
        for (int q = 0; q < 4; ++q) za[q] += sXb[ig * 4 + q][pp] * w;
      }
      const float bb2 = sB2[d64];
#pragma unroll
      for (int q = 0; q < 4; ++q) {
        const int i = ig * 4 + q;
        float corr = 0.f;
#pragma unroll
        for (int j = 0; j < 16; ++j) corr += sC[i][j] * sG2[j][d64];
        sZ2[i][d64] = za[q] + bb2 - corr;
      }
    }
    __syncthreads();  // G

    // ---- XQW = XQ + ln_fwd(Z2_bar) -> overwrite Qb in place
    {
      const int i = tid >> 4, j = tid & 15;
      const f32x4 z = *(const f32x4*)&sZ2[i][j * 4];
      float s1 = z[0] + z[1] + z[2] + z[3];
      float s2 = z[0] * z[0] + z[1] * z[1] + z[2] * z[2] + z[3] * z[3];
#pragma unroll
      for (int o = 8; o; o >>= 1) { s1 += __shfl_xor(s1, o, 16); s2 += __shfl_xor(s2, o, 16); }
      const float mu = s1 * (1.f / 64.f);
      const float rstd = rsqrtf(s2 * (1.f / 64.f) - mu * mu + 1e-6f);
      const f32x4 g = *(const f32x4*)&sLnw[j * 4];
      const f32x4 bb = *(const f32x4*)&sLnb[j * 4];
      const f32x4 xq = *(const f32x4*)&sXQ[i][j * 4];
      f32x4 o4;
#pragma unroll
      for (int e = 0; e < 4; ++e) o4[e] = xq[e] + g[e] * ((z[e] - mu) * rstd) + bb[e];
      *(f32x4*)&Qb[gbase + (long)i * WIDTH + j * 4] = o4;
    }
    // ---- state updates (W1 LDS col, b1, W2 global row RMW, b2)
    {
      float lj[16], nj[16], mj[16];
      const float tok15 = sTok[15];
#pragma unroll
      for (int j = 0; j < 16; ++j) {
        lj[j] = tok15 * sLr[j];
        nj[j] = lj[j] * g1r[j];
        mj[j] = lj[j] * sX2[j][p];
      }
#pragma unroll 4
      for (int dq = 0; dq < 16; ++dq) {
        f32x4 a = {0.f, 0.f, 0.f, 0.f};
#pragma unroll
        for (int j = 0; j < 16; ++j) {
          const f32x4 x = *(const f32x4*)&sX1[j][dq * 4];
          a[0] += nj[j] * x[0]; a[1] += nj[j] * x[1]; a[2] += nj[j] * x[2]; a[3] += nj[j] * x[3];
        }
        f32x4* wp = (f32x4*)&sW1c[p * 64 + ((dq ^ (p & 7)) << 2)];
        f32x4 wv = *wp;
        wv[0] -= a[0]; wv[1] -= a[1]; wv[2] -= a[2]; wv[3] -= a[3];
        *wp = wv;
      }
      {
        float s = 0.f;
#pragma unroll
        for (int j = 0; j < 16; ++j) s += nj[j];
        sB1[p] -= s;
      }
      {
        const float* __restrict__ src = (n == 0) ? (W2in + h * 16384) : W2s;
#pragma unroll 4
        for (int dq = 0; dq < 16; ++dq) {
          f32x4 w = *(const f32x4*)&src[p * 64 + dq * 4];
#pragma unroll
          for (int j = 0; j < 16; ++j) {
            const f32x4 g = *(const f32x4*)&sG2[j][dq * 4];
            w[0] -= mj[j] * g[0]; w[1] -= mj[j] * g[1]; w[2] -= mj[j] * g[2]; w[3] -= mj[j] * g[3];
          }
          *(f32x4*)&W2s[p * 64 + dq * 4] = w;
        }
      }
      if (tid < 64) {
        float s = 0.f;
#pragma unroll
        for (int j = 0; j < 16; ++j) s += lj[j] * sG2[j][tid];
        sB2[tid] -= s;
      }
    }
    __threadfence_block();
    __syncthreads();  // H
  }
}

// ---------------- epilogue: tmp = gelu(G) * ln_fwd(XQW, post_w, post_b)
__global__ __launch_bounds__(256) void epi_kernel(const float* __restrict__ X,
                                                  const float* __restrict__ G,
                                                  const float* __restrict__ pw,
                                                  const float* __restrict__ pb,
                                                  float* __restrict__ T) {
  __shared__ float red[8];
  const int t = blockIdx.x, tid = threadIdx.x;
  const long base = (long)t * 1024 + tid * 4;
  f32x4 x = *(const f32x4*)&X[base];
  float s1 = x[0] + x[1] + x[2] + x[3];
  float s2 = x[0] * x[0] + x[1] * x[1] + x[2] * x[2] + x[3] * x[3];
#pragma unroll
  for (int o = 32; o; o >>= 1) { s1 += __shfl_xor(s1, o, 64); s2 += __shfl_xor(s2, o, 64); }
  const int wv = tid >> 6, ln = tid & 63;
  if (ln == 0) { red[wv] = s1; red[4 + wv] = s2; }
  __syncthreads();
  s1 = red[0] + red[1] + red[2] + red[3];
  s2 = red[4] + red[5] + red[6] + red[7];
  const float mu = s1 * (1.f / 1024.f);
  const float rstd = rsqrtf(s2 * (1.f / 1024.f) - mu * mu + 1e-6f);
  f32x4 g = *(const f32x4*)&G[base];
  f32x4 w = *(const f32x4*)&pw[tid * 4];
  f32x4 bb = *(const f32x4*)&pb[tid * 4];
  f32x4 o4;
#pragma unroll
  for (int e = 0; e < 4; ++e) {
    float y = w[e] * ((x[e] - mu) * rstd) + bb[e];
    o4[e] = gelu_f(g[e]) * y;
  }
  *(f32x4*)&T[base] = o4;
}

extern "C" void kernel_launch(void* const* d_in, const int* in_sizes, int n_in,
                              void* d_out, int out_size, void* d_ws, size_t ws_size,
                              hipStream_t stream) {
  const float* hs  = (const float*)d_in[0];
  const float* Wq  = (const float*)d_in[1];
  const float* Wk  = (const float*)d_in[2];
  const float* Wv  = (const float*)d_in[3];
  const float* Wo  = (const float*)d_in[4];
  const float* Wg  = (const float*)d_in[5];
  const float* lrw = (const float*)d_in[6];
  const float* lrb = (const float*)d_in[7];
  const float* lti = (const float*)d_in[8];
  const float* nw  = (const float*)d_in[9];
  const float* nb  = (const float*)d_in[10];
  const float* W1  = (const float*)d_in[11];
  const float* b1  = (const float*)d_in[12];
  const float* W2  = (const float*)d_in[13];
  const float* b2  = (const float*)d_in[14];
  const float* pw  = (const float*)d_in[15];
  const float* pb  = (const float*)d_in[16];
  float* out = (float*)d_out;
  float* ws = (float*)d_ws;

  // workspace: Q | K | V | G (8M f32 each) | lr_eta (131072) | W2 state (64*16384)
  float* Qb  = ws;
  float* Kb  = ws + 8388608;
  float* Vb  = ws + 16777216;
  float* Gb  = ws + 25165824;
  float* LRb = ws + 33554432;
  float* W2S = ws + 33554432 + 131072;

  dim3 gg(128, 16);
  gemm_bt<<<gg, 256, 0, stream>>>(hs, Wq, Qb);
  gemm_bt<<<gg, 256, 0, stream>>>(hs, Wk, Kb);
  gemm_bt<<<gg, 256, 0, stream>>>(hs, Wv, Vb);
  gemm_bt<<<gg, 256, 0, stream>>>(hs, Wg, Gb);
  lr_kernel<<<8192, 256, 0, stream>>>(hs, lrw, lrb, LRb);
  scan_kernel<<<64, 256, 0, stream>>>(Qb, Kb, Vb, LRb, lti, nw, nb, W1, b1, W2, b2, W2S);
  epi_kernel<<<8192, 256, 0, stream>>>(Qb, Gb, pw, pb, Kb);  // tmp -> Kb (dead after scan)
  gemm_bt<<<gg, 256, 0, stream>>>(Kb, Wo, out);
}